// Round 19
// baseline (647.654 us; speedup 1.0000x reference)
//
#include <hip/hip_runtime.h>
#include <math.h>

#define PI2 6.283185307179586f

typedef __attribute__((ext_vector_type(8))) short bf16x8;
typedef __attribute__((ext_vector_type(4))) float f32x4;

__device__ __forceinline__ float gelu_f(float x) {
    return 0.5f * x * (1.0f + erff(x * 0.7071067811865476f));
}
__device__ __forceinline__ unsigned short f2bf(float f) {
    unsigned int u = __float_as_uint(f);
    u += 0x7FFFu + ((u >> 16) & 1u);
    return (unsigned short)(u >> 16);
}
__device__ __forceinline__ float bf2f(unsigned short h) {
    return __uint_as_float(((unsigned int)h) << 16);
}
__device__ __forceinline__ unsigned int pk(unsigned short a, unsigned short b) {
    return (unsigned int)a | ((unsigned int)b << 16);
}
__device__ __forceinline__ void wsplit(float w, unsigned short* dst) {
    unsigned short h = f2bf(w);
    dst[0] = h;
    dst[128] = f2bf(w - bf2f(h));
}

// ---- fused bases + fc0 + layer-0 analysis (atomic fp32 moment accumulation) ----
template<int NIN>
__global__ __launch_bounds__(256) void k_prep(const float* __restrict__ nodes, const float* __restrict__ modes,
                                              const float* __restrict__ latent, const float* __restrict__ nw,
                                              const float* __restrict__ inp, const float* __restrict__ fcw,
                                              const float* __restrict__ fcb,
                                              unsigned short* __restrict__ FTb, unsigned short* __restrict__ ch0,
                                              unsigned short* __restrict__ wbb,
                                              float* __restrict__ mom, int N) {
    int b = blockIdx.y;
    int tid = threadIdx.x;
    int xl = tid & 127, half = tid >> 7;
    int x = blockIdx.x * 128 + xl;
    __shared__ unsigned short st_c[64][136];
    __shared__ unsigned short st_w[65][136];
    float s0 = 0.5f + 1.5f / (1.0f + expf(-latent[0]));
    float s1 = 0.5f + 1.5f / (1.0f + expf(-latent[1]));
    float n0 = nodes[((size_t)b * N + x) * 2 + 0];
    float n1 = nodes[((size_t)b * N + x) * 2 + 1];
    float wx = nw[(size_t)b * N + x];
    unsigned short* wb = wbb + (size_t)b * 65 * N + x;
    unsigned int fcos[8], fsin[8], fch[16];
    #pragma unroll
    for (int kk = 0; kk < 16; ++kk) {
        int k = half * 16 + kk;
        float m0 = modes[k * 2 + 0] * s0;
        float m1 = modes[k * 2 + 1] * s1;
        float t = PI2 * (n0 * m0 + n1 * m1);
        float s, c;
        sincosf(t, &s, &c);
        unsigned short hc = f2bf(c), hs = f2bf(s);
        if (kk & 1) { fcos[kk >> 1] |= ((unsigned int)hc << 16); fsin[kk >> 1] |= ((unsigned int)hs << 16); }
        else        { fcos[kk >> 1] = hc;                         fsin[kk >> 1] = hs; }
        unsigned short hcw = f2bf(c * wx), hsw = f2bf(s * wx);
        st_w[k][xl] = hcw;
        st_w[32 + k][xl] = hsw;
        wb[(size_t)k * N] = hcw;
        wb[(size_t)(32 + k) * N] = hsw;
    }
    if (half) {
        unsigned short hw = f2bf(wx);
        st_w[64][xl] = hw;
        wb[(size_t)64 * N] = hw;
    }
    float xi[NIN];
    #pragma unroll
    for (int i = 0; i < NIN; ++i) xi[i] = inp[((size_t)b * N + x) * NIN + i];
    #pragma unroll
    for (int cc = 0; cc < 32; ++cc) {
        int c = half * 32 + cc;
        float a = fcb[c];
        #pragma unroll
        for (int i = 0; i < NIN; ++i) a += fcw[c * NIN + i] * xi[i];
        unsigned short h = f2bf(a);
        st_c[c][xl] = h;
        if (cc & 1) fch[cc >> 1] |= ((unsigned int)h << 16);
        else fch[cc >> 1] = h;
    }
    unsigned int* fr = (unsigned int*)(FTb + ((size_t)b * N + x) * 64);
    #pragma unroll
    for (int i = 0; i < 8; ++i) fr[half * 8 + i] = fcos[i];
    #pragma unroll
    for (int i = 0; i < 8; ++i) fr[16 + half * 8 + i] = fsin[i];
    unsigned int* cr = (unsigned int*)(ch0 + ((size_t)b * N + x) * 64);
    #pragma unroll
    for (int i = 0; i < 16; ++i) cr[half * 16 + i] = fch[i];
    __syncthreads();
    int lane = tid & 63, wv = tid >> 6;
    int lm = lane & 15, lg = lane >> 4;
    int ro = wv * 16;
    f32x4 acc[5] = {};
    #pragma unroll
    for (int xs = 0; xs < 128; xs += 32) {
        bf16x8 a = *(const bf16x8*)&st_c[ro + lm][xs + lg * 8];
        #pragma unroll
        for (int ct = 0; ct < 4; ++ct) {
            bf16x8 bw = *(const bf16x8*)&st_w[ct * 16 + lm][xs + lg * 8];
            acc[ct] = __builtin_amdgcn_mfma_f32_16x16x32_bf16(a, bw, acc[ct], 0, 0, 0);
        }
        bf16x8 wf = *(const bf16x8*)&st_w[64][xs + lg * 8];
        acc[4] = __builtin_amdgcn_mfma_f32_16x16x32_bf16(a, wf, acc[4], 0, 0, 0);
    }
    float* mb = mom + (size_t)b * 64 * 66;
    #pragma unroll
    for (int ct = 0; ct < 4; ++ct)
        #pragma unroll
        for (int j = 0; j < 4; ++j)
            atomicAdd(&mb[(ro + lg * 4 + j) * 66 + ct * 16 + lm], acc[ct][j]);
    if (lm == 0) {
        #pragma unroll
        for (int j = 0; j < 4; ++j) atomicAdd(&mb[(ro + lg * 4 + j) * 66 + 64], acc[4][j]);
    }
}

// ---- transpose weights (l,i,o,k)->(l,k,i,o) ----
__global__ __launch_bounds__(256) void k_tw(const float* __restrict__ e_c, const float* __restrict__ e_s,
                                            const float* __restrict__ u_c, const float* __restrict__ u_s,
                                            const float* __restrict__ v_c, const float* __restrict__ v_s,
                                            float* __restrict__ oT) {
    int li = blockIdx.x;
    int a = blockIdx.y;
    const float* in;
    switch (a) {
        case 0: in = e_c; break;
        case 1: in = e_s; break;
        case 2: in = u_c; break;
        case 3: in = u_s; break;
        case 4: in = v_c; break;
        default: in = v_s; break;
    }
    float* outp = oT + (size_t)a * 393216;
    int l = li >> 6, i = li & 63;
    __shared__ float t[32][65];
    int tid = threadIdx.x;
    const float* ib = in + (size_t)l * 131072 + (size_t)i * 2048;
    #pragma unroll
    for (int r = 0; r < 8; ++r) {
        int e = r * 256 + tid;
        t[e & 31][e >> 5] = ib[e];
    }
    __syncthreads();
    float* ob = outp + (size_t)l * 131072 + (size_t)i * 64;
    #pragma unroll
    for (int r = 0; r < 8; ++r) {
        int e = r * 256 + tid;
        ob[(size_t)(e >> 6) * 4096 + (e & 63)] = t[e >> 6][e & 63];
    }
}

// ---- buildW -> WBf[b][o][hi128|lo128] bf16 + bias fp32 ----
__global__ void k_buildW(const float* __restrict__ momu, const float* __restrict__ momv,
                         const float* __restrict__ ecT, const float* __restrict__ esT, const float* __restrict__ ew0,
                         const float* __restrict__ ucT, const float* __restrict__ usT, const float* __restrict__ uw0,
                         const float* __restrict__ vcT, const float* __restrict__ vsT, const float* __restrict__ vw0,
                         const float* __restrict__ wsuw, const float* __restrict__ wsub,
                         const float* __restrict__ wsvw, const float* __restrict__ wsvb,
                         unsigned short* __restrict__ WuBf, unsigned short* __restrict__ WvBf,
                         float* __restrict__ biasU, float* __restrict__ biasV, int do_v) {
    int b = blockIdx.y, j = blockIdx.x, o = threadIdx.x;
    const float* mu = momu + (size_t)b * 64 * 66;
    const float* mv = momv + (size_t)b * 64 * 66;
    unsigned short* Wub = WuBf + ((size_t)b * 64 + o) * 256;
    unsigned short* Wvb = WvBf + ((size_t)b * 64 + o) * 256;
    if (j < 32) {
        int k = j;
        const float* ec = ecT + (size_t)k * 4096;
        const float* es = esT + (size_t)k * 4096;
        const float* uc = ucT + (size_t)k * 4096;
        const float* us = usT + (size_t)k * 4096;
        const float* vc = vcT + (size_t)k * 4096;
        const float* vs = vsT + (size_t)k * 4096;
        float fcu = 0, fsu = 0, fcv = 0, fsv = 0;
        for (int i = 0; i < 64; ++i) {
            float Scv = mv[i * 66 + k], Ssv = mv[i * 66 + 32 + k];
            float Scu = mu[i * 66 + k], Ssu = mu[i * 66 + 32 + k];
            int wi = i * 64 + o;
            float e_c = ec[wi], e_s = es[wi];
            float u_c = uc[wi], u_s = us[wi];
            fcu += Scv * e_c + Ssv * e_s + Scu * u_c + Ssu * u_s;
            fsu += Scv * e_s - Ssv * e_c + Scu * u_s - Ssu * u_c;
            if (do_v) {
                float v_c = vc[wi], v_s = vs[wi];
                fcv += Scv * v_c + Ssv * v_s;
                fsv += Scv * v_s - Ssv * v_c;
            }
        }
        wsplit(2.f * fcu, Wub + k);
        wsplit(-2.f * fsu, Wub + 32 + k);
        if (do_v) {
            wsplit(2.f * fcv, Wvb + k);
            wsplit(-2.f * fsv, Wvb + 32 + k);
        }
    } else {
        for (int c = 0; c < 64; ++c) wsplit(wsuw[o * 64 + c], Wub + 64 + c);
        float f0u = 0;
        for (int i = 0; i < 64; ++i)
            f0u += mv[i * 66 + 64] * ew0[i * 64 + o] + mu[i * 66 + 64] * uw0[i * 64 + o];
        biasU[b * 64 + o] = f0u + wsub[o];
        if (do_v) {
            for (int c = 0; c < 64; ++c) wsplit(wsvw[o * 64 + c], Wvb + 64 + c);
            float f0v = 0;
            for (int i = 0; i < 64; ++i) f0v += mv[i * 66 + 64] * vw0[i * 64 + o];
            biasV[b * 64 + o] = f0v + wsvb[o];
        }
    }
}

// ---- fallback buildW (original layout) ----
__global__ void k_buildW_slow(const float* __restrict__ momu, const float* __restrict__ momv,
                              const float* __restrict__ ewc, const float* __restrict__ ews, const float* __restrict__ ew0,
                              const float* __restrict__ uwc, const float* __restrict__ uws, const float* __restrict__ uw0,
                              const float* __restrict__ vwc, const float* __restrict__ vws, const float* __restrict__ vw0,
                              const float* __restrict__ wsuw, const float* __restrict__ wsub,
                              const float* __restrict__ wsvw, const float* __restrict__ wsvb,
                              unsigned short* __restrict__ WuBf, unsigned short* __restrict__ WvBf,
                              float* __restrict__ biasU, float* __restrict__ biasV, int do_v) {
    int b = blockIdx.y, j = blockIdx.x, o = threadIdx.x;
    const float* mu = momu + (size_t)b * 64 * 66;
    const float* mv = momv + (size_t)b * 64 * 66;
    unsigned short* Wub = WuBf + ((size_t)b * 64 + o) * 256;
    unsigned short* Wvb = WvBf + ((size_t)b * 64 + o) * 256;
    if (j < 32) {
        int k = j;
        float fcu = 0, fsu = 0, fcv = 0, fsv = 0;
        for (int i = 0; i < 64; ++i) {
            float Scv = mv[i * 66 + k], Ssv = mv[i * 66 + 32 + k];
            float Scu = mu[i * 66 + k], Ssu = mu[i * 66 + 32 + k];
            int wi = (i * 64 + o) * 32 + k;
            float ec = ewc[wi], es = ews[wi];
            float uc = uwc[wi], us = uws[wi];
            fcu += Scv * ec + Ssv * es + Scu * uc + Ssu * us;
            fsu += Scv * es - Ssv * ec + Scu * us - Ssu * uc;
            if (do_v) {
                float vc = vwc[wi], vs = vws[wi];
                fcv += Scv * vc + Ssv * vs;
                fsv += Scv * vs - Ssv * vc;
            }
        }
        wsplit(2.f * fcu, Wub + k);
        wsplit(-2.f * fsu, Wub + 32 + k);
        if (do_v) {
            wsplit(2.f * fcv, Wvb + k);
            wsplit(-2.f * fsv, Wvb + 32 + k);
        }
    } else {
        for (int c = 0; c < 64; ++c) wsplit(wsuw[o * 64 + c], Wub + 64 + c);
        float f0u = 0;
        for (int i = 0; i < 64; ++i)
            f0u += mv[i * 66 + 64] * ew0[i * 64 + o] + mu[i * 66 + 64] * uw0[i * 64 + o];
        biasU[b * 64 + o] = f0u + wsub[o];
        if (do_v) {
            for (int c = 0; c < 64; ++c) wsplit(wsvw[o * 64 + c], Wvb + 64 + c);
            float f0v = 0;
            for (int i = 0; i < 64; ++i) f0v += mv[i * 66 + 64] * vw0[i * 64 + o];
            biasV[b * 64 + o] = f0v + wsvb[o];
        }
    }
}

// ---- fused synthesis u+v + moment epilogue; ping-pong ch; atomic moment accumulation ----
__global__ __launch_bounds__(256, 2) void k_synth3(const unsigned short* __restrict__ WuBf,
                                                   const unsigned short* __restrict__ WvBf,
                                                   const float* __restrict__ biasU, const float* __restrict__ biasV,
                                                   const unsigned short* __restrict__ FTb_u,
                                                   const unsigned short* __restrict__ FTb_v,
                                                   const unsigned short* __restrict__ chIn_u,
                                                   const unsigned short* __restrict__ chIn_v,
                                                   unsigned short* __restrict__ chOut_u,
                                                   unsigned short* __restrict__ chOut_v,
                                                   const unsigned short* __restrict__ wbb_u,
                                                   const unsigned short* __restrict__ wbb_v,
                                                   float* __restrict__ momN_u, float* __restrict__ momN_v,
                                                   int NU_, int NV_, int nbu, int act_u, int wch_v) {
    int bx = blockIdx.x, b = blockIdx.y, tid = threadIdx.x;
    const unsigned short *Wb, *FTb, *chIn, *wb;
    const float* bi;
    unsigned short* chOut;
    float* momN;
    int N, act, wch, blk;
    if (bx < nbu) {
        blk = bx; Wb = WuBf; bi = biasU; FTb = FTb_u; chIn = chIn_u; chOut = chOut_u; N = NU_;
        wb = wbb_u + (size_t)b * 65 * NU_;
        momN = momN_u;
        act = act_u; wch = 1;
    } else {
        blk = bx - nbu; Wb = WvBf; bi = biasV; FTb = FTb_v; chIn = chIn_v; chOut = chOut_v; N = NV_;
        wb = wbb_v + (size_t)b * 65 * NV_;
        momN = momN_v;
        act = 1; wch = wch_v;
    }
    int lane = tid & 63, wv = tid >> 6;
    int lm = lane & 15, lg = lane >> 4;
    int ro = wv * 16;
    int r0 = ro + lg * 4;
    int x0 = blk * 128;
    // hoisted moment-phase wbb loads (consumed after barrier)
    bf16x8 wfr[4][5];
    #pragma unroll
    for (int xi = 0; xi < 4; ++xi) {
        int xs = xi * 32;
        #pragma unroll
        for (int ct = 0; ct < 4; ++ct)
            wfr[xi][ct] = *(const bf16x8*)(wb + (size_t)(ct * 16 + lm) * N + x0 + xs + lg * 8);
        wfr[xi][4] = *(const bf16x8*)(wb + (size_t)64 * N + x0 + xs + lg * 8);
    }
    const unsigned short* Wrow = Wb + ((size_t)b * 64 + ro + lm) * 256;
    bf16x8 ahi[4], alo[4];
    #pragma unroll
    for (int kt = 0; kt < 4; ++kt) {
        ahi[kt] = *(const bf16x8*)(Wrow + kt * 32 + lg * 8);
        alo[kt] = *(const bf16x8*)(Wrow + 128 + kt * 32 + lg * 8);
    }
    float bias[4];
    #pragma unroll
    for (int j = 0; j < 4; ++j) bias[j] = bi[b * 64 + ro + lg * 4 + j];
    const unsigned short* fbb = FTb + (size_t)b * N * 64;
    const unsigned short* cib = chIn + (size_t)b * N * 64;
    unsigned short* cob = chOut + (size_t)b * N * 64;
    __shared__ unsigned short st2[64][136];
    f32x4 acc[8] = {};
    #pragma unroll
    for (int hh = 0; hh < 2; ++hh) {
        bf16x8 bfr[4][4];
        #pragma unroll
        for (int xt = 0; xt < 4; ++xt) {
            size_t xr = (size_t)(x0 + (hh * 4 + xt) * 16 + lm) * 64 + lg * 8;
            bfr[xt][0] = *(const bf16x8*)(fbb + xr);
            bfr[xt][1] = *(const bf16x8*)(fbb + xr + 32);
            bfr[xt][2] = *(const bf16x8*)(cib + xr);
            bfr[xt][3] = *(const bf16x8*)(cib + xr + 32);
        }
        #pragma unroll
        for (int xt = 0; xt < 4; ++xt)
            #pragma unroll
            for (int kt = 0; kt < 4; ++kt) {
                acc[hh * 4 + xt] = __builtin_amdgcn_mfma_f32_16x16x32_bf16(ahi[kt], bfr[xt][kt], acc[hh * 4 + xt], 0, 0, 0);
                acc[hh * 4 + xt] = __builtin_amdgcn_mfma_f32_16x16x32_bf16(alo[kt], bfr[xt][kt], acc[hh * 4 + xt], 0, 0, 0);
            }
    }
    // no read-write hazard: ping-pong buffers
    #pragma unroll
    for (int xt = 0; xt < 8; ++xt) {
        int xl = xt * 16 + lm;
        float v[4];
        #pragma unroll
        for (int j = 0; j < 4; ++j) {
            v[j] = acc[xt][j] + bias[j];
            if (act) v[j] = gelu_f(v[j]);
        }
        unsigned short h[4];
        #pragma unroll
        for (int j = 0; j < 4; ++j) h[j] = f2bf(v[j]);
        st2[r0 + 0][xl] = h[0];
        st2[r0 + 1][xl] = h[1];
        st2[r0 + 2][xl] = h[2];
        st2[r0 + 3][xl] = h[3];
        if (wch) {
            unsigned int* dst = (unsigned int*)(cob + (size_t)(x0 + xl) * 64 + r0);
            dst[0] = pk(h[0], h[1]);
            dst[1] = pk(h[2], h[3]);
        }
    }
    __syncthreads();  // st2 visible to moment phase
    f32x4 macc[5] = {};
    #pragma unroll
    for (int xi = 0; xi < 4; ++xi) {
        int xs = xi * 32;
        bf16x8 a = *(const bf16x8*)&st2[ro + lm][xs + lg * 8];
        #pragma unroll
        for (int ct = 0; ct < 4; ++ct)
            macc[ct] = __builtin_amdgcn_mfma_f32_16x16x32_bf16(a, wfr[xi][ct], macc[ct], 0, 0, 0);
        macc[4] = __builtin_amdgcn_mfma_f32_16x16x32_bf16(a, wfr[xi][4], macc[4], 0, 0, 0);
    }
    float* mb = momN + (size_t)b * 64 * 66;
    #pragma unroll
    for (int ct = 0; ct < 4; ++ct)
        #pragma unroll
        for (int j = 0; j < 4; ++j)
            atomicAdd(&mb[(r0 + j) * 66 + ct * 16 + lm], macc[ct][j]);
    if (lm == 0) {
        #pragma unroll
        for (int j = 0; j < 4; ++j) atomicAdd(&mb[(r0 + j) * 66 + 64], macc[4][j]);
    }
}

// ---- fused last-layer u-synthesis + fc1(gelu) + fc2 -> out ----
__global__ __launch_bounds__(256, 2) void k_synthfc(const unsigned short* __restrict__ WuBf,
                                                    const float* __restrict__ biasU,
                                                    const unsigned short* __restrict__ FTb_u,
                                                    const unsigned short* __restrict__ chIn_u,
                                                    const float* __restrict__ w1, const float* __restrict__ b1,
                                                    const float* __restrict__ w2, const float* __restrict__ b2,
                                                    float* __restrict__ out, int N) {
    int blk = blockIdx.x, b = blockIdx.y, tid = threadIdx.x;
    int lane = tid & 63, wv = tid >> 6;
    int lm = lane & 15, lg = lane >> 4;
    int ro = wv * 16;
    int r0 = ro + lg * 4;
    int x0 = blk * 128;
    int f0 = wv * 32;
    float wtmp[2][2][8];
    #pragma unroll
    for (int ft = 0; ft < 2; ++ft)
        #pragma unroll
        for (int kt = 0; kt < 2; ++kt) {
            const float* wp = w1 + (size_t)(f0 + ft * 16 + lm) * 64 + kt * 32 + lg * 8;
            *(float4*)&wtmp[ft][kt][0] = *(const float4*)wp;
            *(float4*)&wtmp[ft][kt][4] = *(const float4*)(wp + 4);
        }
    const unsigned short* Wrow = WuBf + ((size_t)b * 64 + ro + lm) * 256;
    bf16x8 ahi[4], alo[4];
    #pragma unroll
    for (int kt = 0; kt < 4; ++kt) {
        ahi[kt] = *(const bf16x8*)(Wrow + kt * 32 + lg * 8);
        alo[kt] = *(const bf16x8*)(Wrow + 128 + kt * 32 + lg * 8);
    }
    float bias[4];
    #pragma unroll
    for (int j = 0; j < 4; ++j) bias[j] = biasU[b * 64 + ro + lg * 4 + j];
    const unsigned short* fbb = FTb_u + (size_t)b * N * 64;
    const unsigned short* cib = chIn_u + (size_t)b * N * 64;
    __shared__ unsigned short st2t[128][72];
    __shared__ float red[4][8][16];
    f32x4 acc[8] = {};
    #pragma unroll
    for (int hh = 0; hh < 2; ++hh) {
        bf16x8 bfr[4][4];
        #pragma unroll
        for (int xt = 0; xt < 4; ++xt) {
            size_t xr = (size_t)(x0 + (hh * 4 + xt) * 16 + lm) * 64 + lg * 8;
            bfr[xt][0] = *(const bf16x8*)(fbb + xr);
            bfr[xt][1] = *(const bf16x8*)(fbb + xr + 32);
            bfr[xt][2] = *(const bf16x8*)(cib + xr);
            bfr[xt][3] = *(const bf16x8*)(cib + xr + 32);
        }
        #pragma unroll
        for (int xt = 0; xt < 4; ++xt)
            #pragma unroll
            for (int kt = 0; kt < 4; ++kt) {
                acc[hh * 4 + xt] = __builtin_amdgcn_mfma_f32_16x16x32_bf16(ahi[kt], bfr[xt][kt], acc[hh * 4 + xt], 0, 0, 0);
                acc[hh * 4 + xt] = __builtin_amdgcn_mfma_f32_16x16x32_bf16(alo[kt], bfr[xt][kt], acc[hh * 4 + xt], 0, 0, 0);
            }
    }
    #pragma unroll
    for (int xt = 0; xt < 8; ++xt) {
        int xl = xt * 16 + lm;
        float v0 = acc[xt][0] + bias[0];
        float v1 = acc[xt][1] + bias[1];
        float v2 = acc[xt][2] + bias[2];
        float v3 = acc[xt][3] + bias[3];
        *(unsigned int*)&st2t[xl][r0] = pk(f2bf(v0), f2bf(v1));
        *(unsigned int*)&st2t[xl][r0 + 2] = pk(f2bf(v2), f2bf(v3));
    }
    __syncthreads();
    bf16x8 whi[2][2], wlo[2][2];
    #pragma unroll
    for (int ft = 0; ft < 2; ++ft)
        #pragma unroll
        for (int kt = 0; kt < 2; ++kt)
            #pragma unroll
            for (int i = 0; i < 8; ++i) {
                unsigned short h = f2bf(wtmp[ft][kt][i]);
                whi[ft][kt][i] = (short)h;
                wlo[ft][kt][i] = (short)f2bf(wtmp[ft][kt][i] - bf2f(h));
            }
    float b1v[2][4], w2v[2][4];
    #pragma unroll
    for (int ft = 0; ft < 2; ++ft)
        #pragma unroll
        for (int j = 0; j < 4; ++j) {
            int f = f0 + ft * 16 + lg * 4 + j;
            b1v[ft][j] = b1[f];
            w2v[ft][j] = w2[f];
        }
    f32x4 facc[8][2] = {};
    #pragma unroll
    for (int xt = 0; xt < 8; ++xt) {
        int xl = xt * 16 + lm;
        bf16x8 bf0 = *(const bf16x8*)&st2t[xl][lg * 8];
        bf16x8 bf1 = *(const bf16x8*)&st2t[xl][32 + lg * 8];
        #pragma unroll
        for (int ft = 0; ft < 2; ++ft) {
            facc[xt][ft] = __builtin_amdgcn_mfma_f32_16x16x32_bf16(whi[ft][0], bf0, facc[xt][ft], 0, 0, 0);
            facc[xt][ft] = __builtin_amdgcn_mfma_f32_16x16x32_bf16(wlo[ft][0], bf0, facc[xt][ft], 0, 0, 0);
            facc[xt][ft] = __builtin_amdgcn_mfma_f32_16x16x32_bf16(whi[ft][1], bf1, facc[xt][ft], 0, 0, 0);
            facc[xt][ft] = __builtin_amdgcn_mfma_f32_16x16x32_bf16(wlo[ft][1], bf1, facc[xt][ft], 0, 0, 0);
        }
    }
    #pragma unroll
    for (int xt = 0; xt < 8; ++xt) {
        float s = 0.f;
        #pragma unroll
        for (int ft = 0; ft < 2; ++ft)
            #pragma unroll
            for (int j = 0; j < 4; ++j) {
                float v = facc[xt][ft][j] + b1v[ft][j];
                s += w2v[ft][j] * gelu_f(v);
            }
        s += __shfl_xor(s, 16, 64);
        s += __shfl_xor(s, 32, 64);
        if (lg == 0) red[wv][xt][lm] = s;
    }
    __syncthreads();
    if (tid < 128) {
        int xt = tid >> 4, lmm = tid & 15;
        float s = b2[0] + red[0][xt][lmm] + red[1][xt][lmm] + red[2][xt][lmm] + red[3][xt][lmm];
        out[(size_t)b * N + x0 + tid] = s;
    }
}

extern "C" void kernel_launch(void* const* d_in, const int* in_sizes, int n_in,
                              void* d_out, int out_size, void* d_ws, size_t ws_size,
                              hipStream_t stream) {
    const float* u_in = (const float*)d_in[0];
    const float* v_in = (const float*)d_in[1];
    const float* nodes_u = (const float*)d_in[3];
    const float* nodes_v = (const float*)d_in[4];
    const float* nwu = (const float*)d_in[5];
    const float* nwv = (const float*)d_in[6];
    const float* modes = (const float*)d_in[7];
    const float* latent = (const float*)d_in[8];
    const float* fc0uw = (const float*)d_in[9];
    const float* fc0ub = (const float*)d_in[10];
    const float* fc0vw = (const float*)d_in[11];
    const float* fc0vb = (const float*)d_in[12];
    const float* ewc = (const float*)d_in[13];
    const float* ews = (const float*)d_in[14];
    const float* ew0 = (const float*)d_in[15];
    const float* uwc = (const float*)d_in[16];
    const float* uws = (const float*)d_in[17];
    const float* uw0 = (const float*)d_in[18];
    const float* vwc = (const float*)d_in[19];
    const float* vws = (const float*)d_in[20];
    const float* vw0 = (const float*)d_in[21];
    const float* wsuw = (const float*)d_in[22];
    const float* wsub = (const float*)d_in[23];
    const float* wsvw = (const float*)d_in[24];
    const float* wsvb = (const float*)d_in[25];
    const float* fc1w = (const float*)d_in[26];
    const float* fc1b = (const float*)d_in[27];
    const float* fc2w = (const float*)d_in[28];
    const float* fc2b = (const float*)d_in[29];
    float* out = (float*)d_out;

    const int B = 4, NU = 65536, NV = 16384;
    const size_t MOMSZ = (size_t)B * 64 * 66;  // per u/v segment

    unsigned short* FTb_u = (unsigned short*)d_ws;
    unsigned short* FTb_v = FTb_u + (size_t)B * NU * 64;
    unsigned short* chU0 = FTb_v + (size_t)B * NV * 64;
    unsigned short* chU1 = chU0 + (size_t)B * NU * 64;
    unsigned short* chV0 = chU1 + (size_t)B * NU * 64;
    unsigned short* chV1 = chV0 + (size_t)B * NV * 64;
    unsigned short* wbb_u = chV1 + (size_t)B * NV * 64;
    unsigned short* wbb_v = wbb_u + (size_t)B * 65 * NU;
    float* momA = (float*)(wbb_v + (size_t)B * 65 * NV);   // [u | v]
    float* momB = momA + 2 * MOMSZ;
    unsigned short* WuBf = (unsigned short*)(momB + 2 * MOMSZ);
    unsigned short* WvBf = WuBf + (size_t)B * 64 * 256;
    float* biasU = (float*)(WvBf + (size_t)B * 64 * 256);
    float* biasV = biasU + B * 64;
    float* wT = biasV + B * 64;
    size_t need_T = (size_t)((char*)(wT + 6 * 393216) - (char*)d_ws);
    int use_T = (ws_size >= need_T) ? 1 : 0;

    // moments for layer 0 accumulate into momA (atomic)
    hipMemsetAsync(momA, 0, 2 * MOMSZ * sizeof(float), stream);
    k_prep<2><<<dim3(NU / 128, B), 256, 0, stream>>>(nodes_u, modes, latent, nwu, u_in, fc0uw, fc0ub,
                                                     FTb_u, chU0, wbb_u, momA /*u*/, NU);
    k_prep<3><<<dim3(NV / 128, B), 256, 0, stream>>>(nodes_v, modes, latent, nwv, v_in, fc0vw, fc0vb,
                                                     FTb_v, chV0, wbb_v, momA + MOMSZ /*v*/, NV);
    if (use_T)
        k_tw<<<dim3(192, 6), 256, 0, stream>>>(ewc, ews, uwc, uws, vwc, vws, wT);

    for (int l = 0; l < 3; ++l) {
        int do_v = (l < 2) ? 1 : 0;
        float* momCur = (l & 1) ? momB : momA;   // l0:A, l1:B, l2:A
        float* momNext = (l & 1) ? momA : momB;  // accumulation target for l+1
        if (use_T) {
            k_buildW<<<dim3(33, B), 64, 0, stream>>>(momCur, momCur + MOMSZ,
                wT + 0 * 393216 + l * 131072, wT + 1 * 393216 + l * 131072, ew0 + (size_t)l * 64 * 64,
                wT + 2 * 393216 + l * 131072, wT + 3 * 393216 + l * 131072, uw0 + (size_t)l * 64 * 64,
                wT + 4 * 393216 + l * 131072, wT + 5 * 393216 + l * 131072, vw0 + (size_t)l * 64 * 64,
                wsuw + l * 64 * 64, wsub + l * 64, wsvw + l * 64 * 64, wsvb + l * 64,
                WuBf, WvBf, biasU, biasV, do_v);
        } else {
            k_buildW_slow<<<dim3(33, B), 64, 0, stream>>>(momCur, momCur + MOMSZ,
                ewc + (size_t)l * 64 * 64 * 32, ews + (size_t)l * 64 * 64 * 32, ew0 + (size_t)l * 64 * 64,
                uwc + (size_t)l * 64 * 64 * 32, uws + (size_t)l * 64 * 64 * 32, uw0 + (size_t)l * 64 * 64,
                vwc + (size_t)l * 64 * 64 * 32, vws + (size_t)l * 64 * 64 * 32, vw0 + (size_t)l * 64 * 64,
                wsuw + l * 64 * 64, wsub + l * 64, wsvw + l * 64 * 64, wsvb + l * 64,
                WuBf, WvBf, biasU, biasV, do_v);
        }
        if (l < 2) {
            hipMemsetAsync(momNext, 0, 2 * MOMSZ * sizeof(float), stream);
            int nbu = NU / 128;
            int nbx = nbu + NV / 128;
            const unsigned short* chInU = (l & 1) ? chU1 : chU0;
            unsigned short* chOutU = (l & 1) ? chU0 : chU1;
            const unsigned short* chInV = (l & 1) ? chV1 : chV0;
            unsigned short* chOutV = (l & 1) ? chV0 : chV1;
            int wch_v = (l == 0) ? 1 : 0;
            k_synth3<<<dim3(nbx, B), 256, 0, stream>>>(WuBf, WvBf, biasU, biasV,
                                                       FTb_u, FTb_v, chInU, chInV, chOutU, chOutV,
                                                       wbb_u, wbb_v, momNext, momNext + MOMSZ,
                                                       NU, NV, nbu, 1 /*act_u*/, wch_v);
        } else {
            k_synthfc<<<dim3(NU / 128, B), 256, 0, stream>>>(WuBf, biasU, FTb_u, chU0,
                                                             fc1w, fc1b, fc2w, fc2b, out, NU);
        }
    }
}

// Round 20
// 446.455 us; speedup vs baseline: 1.4507x; 1.4507x over previous
//
#include <hip/hip_runtime.h>
#include <math.h>

#define PI2 6.283185307179586f

typedef __attribute__((ext_vector_type(8))) short bf16x8;
typedef __attribute__((ext_vector_type(4))) float f32x4;

__device__ __forceinline__ float gelu_f(float x) {
    return 0.5f * x * (1.0f + erff(x * 0.7071067811865476f));
}
__device__ __forceinline__ unsigned short f2bf(float f) {
    unsigned int u = __float_as_uint(f);
    u += 0x7FFFu + ((u >> 16) & 1u);
    return (unsigned short)(u >> 16);
}
__device__ __forceinline__ float bf2f(unsigned short h) {
    return __uint_as_float(((unsigned int)h) << 16);
}
__device__ __forceinline__ unsigned int pk(unsigned short a, unsigned short b) {
    return (unsigned int)a | ((unsigned int)b << 16);
}
__device__ __forceinline__ void wsplit(float w, unsigned short* dst) {
    unsigned short h = f2bf(w);
    dst[0] = h;
    dst[128] = f2bf(w - bf2f(h));
}

// ---- fused bases + fc0 + layer-0 analysis.
// FTb[b][x][64] = [cos32|sin32]; ch0[b][x][64] = fc0 channels (ping-pong buffer 0). ----
template<int NIN>
__global__ __launch_bounds__(256) void k_prep(const float* __restrict__ nodes, const float* __restrict__ modes,
                                              const float* __restrict__ latent, const float* __restrict__ nw,
                                              const float* __restrict__ inp, const float* __restrict__ fcw,
                                              const float* __restrict__ fcb,
                                              unsigned short* __restrict__ FTb, unsigned short* __restrict__ ch0,
                                              unsigned short* __restrict__ wbb,
                                              unsigned short* __restrict__ part, int N) {
    int b = blockIdx.y;
    int tid = threadIdx.x;
    int xl = tid & 127, half = tid >> 7;
    int x = blockIdx.x * 128 + xl;
    __shared__ unsigned short st_c[64][136];
    __shared__ unsigned short st_w[65][136];
    float s0 = 0.5f + 1.5f / (1.0f + expf(-latent[0]));
    float s1 = 0.5f + 1.5f / (1.0f + expf(-latent[1]));
    float n0 = nodes[((size_t)b * N + x) * 2 + 0];
    float n1 = nodes[((size_t)b * N + x) * 2 + 1];
    float wx = nw[(size_t)b * N + x];
    unsigned short* wb = wbb + (size_t)b * 65 * N + x;
    unsigned int fcos[8], fsin[8], fch[16];
    #pragma unroll
    for (int kk = 0; kk < 16; ++kk) {
        int k = half * 16 + kk;
        float m0 = modes[k * 2 + 0] * s0;
        float m1 = modes[k * 2 + 1] * s1;
        float t = PI2 * (n0 * m0 + n1 * m1);
        float s, c;
        sincosf(t, &s, &c);
        unsigned short hc = f2bf(c), hs = f2bf(s);
        if (kk & 1) { fcos[kk >> 1] |= ((unsigned int)hc << 16); fsin[kk >> 1] |= ((unsigned int)hs << 16); }
        else        { fcos[kk >> 1] = hc;                         fsin[kk >> 1] = hs; }
        unsigned short hcw = f2bf(c * wx), hsw = f2bf(s * wx);
        st_w[k][xl] = hcw;
        st_w[32 + k][xl] = hsw;
        wb[(size_t)k * N] = hcw;
        wb[(size_t)(32 + k) * N] = hsw;
    }
    if (half) {
        unsigned short hw = f2bf(wx);
        st_w[64][xl] = hw;
        wb[(size_t)64 * N] = hw;
    }
    float xi[NIN];
    #pragma unroll
    for (int i = 0; i < NIN; ++i) xi[i] = inp[((size_t)b * N + x) * NIN + i];
    #pragma unroll
    for (int cc = 0; cc < 32; ++cc) {
        int c = half * 32 + cc;
        float a = fcb[c];
        #pragma unroll
        for (int i = 0; i < NIN; ++i) a += fcw[c * NIN + i] * xi[i];
        unsigned short h = f2bf(a);
        st_c[c][xl] = h;
        if (cc & 1) fch[cc >> 1] |= ((unsigned int)h << 16);
        else fch[cc >> 1] = h;
    }
    unsigned int* fr = (unsigned int*)(FTb + ((size_t)b * N + x) * 64);
    #pragma unroll
    for (int i = 0; i < 8; ++i) fr[half * 8 + i] = fcos[i];
    #pragma unroll
    for (int i = 0; i < 8; ++i) fr[16 + half * 8 + i] = fsin[i];
    unsigned int* cr = (unsigned int*)(ch0 + ((size_t)b * N + x) * 64);
    #pragma unroll
    for (int i = 0; i < 16; ++i) cr[half * 16 + i] = fch[i];
    __syncthreads();
    int lane = tid & 63, wv = tid >> 6;
    int lm = lane & 15, lg = lane >> 4;
    int ro = wv * 16;
    f32x4 acc[5] = {};
    #pragma unroll
    for (int xs = 0; xs < 128; xs += 32) {
        bf16x8 a = *(const bf16x8*)&st_c[ro + lm][xs + lg * 8];
        #pragma unroll
        for (int ct = 0; ct < 4; ++ct) {
            bf16x8 bw = *(const bf16x8*)&st_w[ct * 16 + lm][xs + lg * 8];
            acc[ct] = __builtin_amdgcn_mfma_f32_16x16x32_bf16(a, bw, acc[ct], 0, 0, 0);
        }
        bf16x8 wf = *(const bf16x8*)&st_w[64][xs + lg * 8];
        acc[4] = __builtin_amdgcn_mfma_f32_16x16x32_bf16(a, wf, acc[4], 0, 0, 0);
    }
    unsigned short* pb = part + (size_t)(b * (N / 128) + blockIdx.x) * 64 * 66;
    #pragma unroll
    for (int ct = 0; ct < 4; ++ct)
        #pragma unroll
        for (int j = 0; j < 4; ++j)
            pb[(ro + lg * 4 + j) * 66 + ct * 16 + lm] = f2bf(acc[ct][j]);
    if (lm == 0) {
        #pragma unroll
        for (int j = 0; j < 4; ++j) pb[(ro + lg * 4 + j) * 66 + 64] = f2bf(acc[4][j]);
    }
}

// ---- reduce bf16 partials u+v -> mom fp32 ----
__global__ __launch_bounds__(256) void k_reduce2(const unsigned short* __restrict__ part_u,
                                                 const unsigned short* __restrict__ part_v,
                                                 float* __restrict__ momu, float* __restrict__ momv,
                                                 int chu, int chv, int B_) {
    int by = blockIdx.y;
    const unsigned short* p;
    float* m;
    int nch, b;
    if (by < B_) { b = by; p = part_u; m = momu; nch = chu; }
    else { b = by - B_; p = part_v; m = momv; nch = chv; }
    int eg = threadIdx.x >> 3;
    int sp = threadIdx.x & 7;
    int e = blockIdx.x * 32 + eg;
    __shared__ float red[32][8];
    float s = 0.f;
    int row = 0, col = 0;
    if (e < 64 * 65) {
        row = e / 65; col = e % 65;
        const unsigned short* pp = p + ((size_t)(b * nch) * 64 + row) * 66 + col;
        for (int c = sp; c < nch; c += 8)
            s += bf2f(pp[(size_t)c * 64 * 66]);
    }
    red[eg][sp] = s;
    __syncthreads();
    if (sp == 0 && e < 64 * 65) {
        float t = 0.f;
        #pragma unroll
        for (int i = 0; i < 8; ++i) t += red[eg][i];
        m[((size_t)b * 64 + row) * 66 + col] = t;
    }
}

// ---- transpose weights (l,i,o,k)->(l,k,i,o) ----
__global__ __launch_bounds__(256) void k_tw(const float* __restrict__ e_c, const float* __restrict__ e_s,
                                            const float* __restrict__ u_c, const float* __restrict__ u_s,
                                            const float* __restrict__ v_c, const float* __restrict__ v_s,
                                            float* __restrict__ oT) {
    int li = blockIdx.x;
    int a = blockIdx.y;
    const float* in;
    switch (a) {
        case 0: in = e_c; break;
        case 1: in = e_s; break;
        case 2: in = u_c; break;
        case 3: in = u_s; break;
        case 4: in = v_c; break;
        default: in = v_s; break;
    }
    float* outp = oT + (size_t)a * 393216;
    int l = li >> 6, i = li & 63;
    __shared__ float t[32][65];
    int tid = threadIdx.x;
    const float* ib = in + (size_t)l * 131072 + (size_t)i * 2048;
    #pragma unroll
    for (int r = 0; r < 8; ++r) {
        int e = r * 256 + tid;
        t[e & 31][e >> 5] = ib[e];
    }
    __syncthreads();
    float* ob = outp + (size_t)l * 131072 + (size_t)i * 64;
    #pragma unroll
    for (int r = 0; r < 8; ++r) {
        int e = r * 256 + tid;
        ob[(size_t)(e >> 6) * 4096 + (e & 63)] = t[e >> 6][e & 63];
    }
}

// ---- buildW -> WBf[b][o][hi128|lo128] bf16 + bias fp32 ----
__global__ void k_buildW(const float* __restrict__ momu, const float* __restrict__ momv,
                         const float* __restrict__ ecT, const float* __restrict__ esT, const float* __restrict__ ew0,
                         const float* __restrict__ ucT, const float* __restrict__ usT, const float* __restrict__ uw0,
                         const float* __restrict__ vcT, const float* __restrict__ vsT, const float* __restrict__ vw0,
                         const float* __restrict__ wsuw, const float* __restrict__ wsub,
                         const float* __restrict__ wsvw, const float* __restrict__ wsvb,
                         unsigned short* __restrict__ WuBf, unsigned short* __restrict__ WvBf,
                         float* __restrict__ biasU, float* __restrict__ biasV, int do_v) {
    int b = blockIdx.y, j = blockIdx.x, o = threadIdx.x;
    const float* mu = momu + (size_t)b * 64 * 66;
    const float* mv = momv + (size_t)b * 64 * 66;
    unsigned short* Wub = WuBf + ((size_t)b * 64 + o) * 256;
    unsigned short* Wvb = WvBf + ((size_t)b * 64 + o) * 256;
    if (j < 32) {
        int k = j;
        const float* ec = ecT + (size_t)k * 4096;
        const float* es = esT + (size_t)k * 4096;
        const float* uc = ucT + (size_t)k * 4096;
        const float* us = usT + (size_t)k * 4096;
        const float* vc = vcT + (size_t)k * 4096;
        const float* vs = vsT + (size_t)k * 4096;
        float fcu = 0, fsu = 0, fcv = 0, fsv = 0;
        for (int i = 0; i < 64; ++i) {
            float Scv = mv[i * 66 + k], Ssv = mv[i * 66 + 32 + k];
            float Scu = mu[i * 66 + k], Ssu = mu[i * 66 + 32 + k];
            int wi = i * 64 + o;
            float e_c = ec[wi], e_s = es[wi];
            float u_c = uc[wi], u_s = us[wi];
            fcu += Scv * e_c + Ssv * e_s + Scu * u_c + Ssu * u_s;
            fsu += Scv * e_s - Ssv * e_c + Scu * u_s - Ssu * u_c;
            if (do_v) {
                float v_c = vc[wi], v_s = vs[wi];
                fcv += Scv * v_c + Ssv * v_s;
                fsv += Scv * v_s - Ssv * v_c;
            }
        }
        wsplit(2.f * fcu, Wub + k);
        wsplit(-2.f * fsu, Wub + 32 + k);
        if (do_v) {
            wsplit(2.f * fcv, Wvb + k);
            wsplit(-2.f * fsv, Wvb + 32 + k);
        }
    } else {
        for (int c = 0; c < 64; ++c) wsplit(wsuw[o * 64 + c], Wub + 64 + c);
        float f0u = 0;
        for (int i = 0; i < 64; ++i)
            f0u += mv[i * 66 + 64] * ew0[i * 64 + o] + mu[i * 66 + 64] * uw0[i * 64 + o];
        biasU[b * 64 + o] = f0u + wsub[o];
        if (do_v) {
            for (int c = 0; c < 64; ++c) wsplit(wsvw[o * 64 + c], Wvb + 64 + c);
            float f0v = 0;
            for (int i = 0; i < 64; ++i) f0v += mv[i * 66 + 64] * vw0[i * 64 + o];
            biasV[b * 64 + o] = f0v + wsvb[o];
        }
    }
}

// ---- fallback buildW (original layout) ----
__global__ void k_buildW_slow(const float* __restrict__ momu, const float* __restrict__ momv,
                              const float* __restrict__ ewc, const float* __restrict__ ews, const float* __restrict__ ew0,
                              const float* __restrict__ uwc, const float* __restrict__ uws, const float* __restrict__ uw0,
                              const float* __restrict__ vwc, const float* __restrict__ vws, const float* __restrict__ vw0,
                              const float* __restrict__ wsuw, const float* __restrict__ wsub,
                              const float* __restrict__ wsvw, const float* __restrict__ wsvb,
                              unsigned short* __restrict__ WuBf, unsigned short* __restrict__ WvBf,
                              float* __restrict__ biasU, float* __restrict__ biasV, int do_v) {
    int b = blockIdx.y, j = blockIdx.x, o = threadIdx.x;
    const float* mu = momu + (size_t)b * 64 * 66;
    const float* mv = momv + (size_t)b * 64 * 66;
    unsigned short* Wub = WuBf + ((size_t)b * 64 + o) * 256;
    unsigned short* Wvb = WvBf + ((size_t)b * 64 + o) * 256;
    if (j < 32) {
        int k = j;
        float fcu = 0, fsu = 0, fcv = 0, fsv = 0;
        for (int i = 0; i < 64; ++i) {
            float Scv = mv[i * 66 + k], Ssv = mv[i * 66 + 32 + k];
            float Scu = mu[i * 66 + k], Ssu = mu[i * 66 + 32 + k];
            int wi = (i * 64 + o) * 32 + k;
            float ec = ewc[wi], es = ews[wi];
            float uc = uwc[wi], us = uws[wi];
            fcu += Scv * ec + Ssv * es + Scu * uc + Ssu * us;
            fsu += Scv * es - Ssv * ec + Scu * us - Ssu * uc;
            if (do_v) {
                float vc = vwc[wi], vs = vws[wi];
                fcv += Scv * vc + Ssv * vs;
                fsv += Scv * vs - Ssv * vc;
            }
        }
        wsplit(2.f * fcu, Wub + k);
        wsplit(-2.f * fsu, Wub + 32 + k);
        if (do_v) {
            wsplit(2.f * fcv, Wvb + k);
            wsplit(-2.f * fsv, Wvb + 32 + k);
        }
    } else {
        for (int c = 0; c < 64; ++c) wsplit(wsuw[o * 64 + c], Wub + 64 + c);
        float f0u = 0;
        for (int i = 0; i < 64; ++i)
            f0u += mv[i * 66 + 64] * ew0[i * 64 + o] + mu[i * 66 + 64] * uw0[i * 64 + o];
        biasU[b * 64 + o] = f0u + wsub[o];
        if (do_v) {
            for (int c = 0; c < 64; ++c) wsplit(wsvw[o * 64 + c], Wvb + 64 + c);
            float f0v = 0;
            for (int i = 0; i < 64; ++i) f0v += mv[i * 66 + 64] * vw0[i * 64 + o];
            biasV[b * 64 + o] = f0v + wsvb[o];
        }
    }
}

// ---- fused synthesis u+v + moment epilogue; ping-pong ch buffers => ONE barrier ----
__global__ __launch_bounds__(256, 2) void k_synth3(const unsigned short* __restrict__ WuBf,
                                                   const unsigned short* __restrict__ WvBf,
                                                   const float* __restrict__ biasU, const float* __restrict__ biasV,
                                                   const unsigned short* __restrict__ FTb_u,
                                                   const unsigned short* __restrict__ FTb_v,
                                                   const unsigned short* __restrict__ chIn_u,
                                                   const unsigned short* __restrict__ chIn_v,
                                                   unsigned short* __restrict__ chOut_u,
                                                   unsigned short* __restrict__ chOut_v,
                                                   const unsigned short* __restrict__ wbb_u,
                                                   const unsigned short* __restrict__ wbb_v,
                                                   unsigned short* __restrict__ part_u, unsigned short* __restrict__ part_v,
                                                   int NU_, int NV_, int nbu, int act_u, int wch_v) {
    int bx = blockIdx.x, b = blockIdx.y, tid = threadIdx.x;
    const unsigned short *Wb, *FTb, *chIn, *wb;
    const float* bi;
    unsigned short *chOut, *pb;
    int N, act, wch, blk;
    if (bx < nbu) {
        blk = bx; Wb = WuBf; bi = biasU; FTb = FTb_u; chIn = chIn_u; chOut = chOut_u; N = NU_;
        wb = wbb_u + (size_t)b * 65 * NU_;
        pb = part_u + (size_t)(b * (NU_ / 128) + blk) * 64 * 66;
        act = act_u; wch = 1;
    } else {
        blk = bx - nbu; Wb = WvBf; bi = biasV; FTb = FTb_v; chIn = chIn_v; chOut = chOut_v; N = NV_;
        wb = wbb_v + (size_t)b * 65 * NV_;
        pb = part_v + (size_t)(b * (NV_ / 128) + blk) * 64 * 66;
        act = 1; wch = wch_v;
    }
    int lane = tid & 63, wv = tid >> 6;
    int lm = lane & 15, lg = lane >> 4;
    int ro = wv * 16;
    int r0 = ro + lg * 4;
    int x0 = blk * 128;
    // hoisted moment-phase wbb loads (consumed after barrier)
    bf16x8 wfr[4][5];
    #pragma unroll
    for (int xi = 0; xi < 4; ++xi) {
        int xs = xi * 32;
        #pragma unroll
        for (int ct = 0; ct < 4; ++ct)
            wfr[xi][ct] = *(const bf16x8*)(wb + (size_t)(ct * 16 + lm) * N + x0 + xs + lg * 8);
        wfr[xi][4] = *(const bf16x8*)(wb + (size_t)64 * N + x0 + xs + lg * 8);
    }
    const unsigned short* Wrow = Wb + ((size_t)b * 64 + ro + lm) * 256;
    bf16x8 ahi[4], alo[4];
    #pragma unroll
    for (int kt = 0; kt < 4; ++kt) {
        ahi[kt] = *(const bf16x8*)(Wrow + kt * 32 + lg * 8);
        alo[kt] = *(const bf16x8*)(Wrow + 128 + kt * 32 + lg * 8);
    }
    float bias[4];
    #pragma unroll
    for (int j = 0; j < 4; ++j) bias[j] = bi[b * 64 + ro + lg * 4 + j];
    const unsigned short* fbb = FTb + (size_t)b * N * 64;
    const unsigned short* cib = chIn + (size_t)b * N * 64;
    unsigned short* cob = chOut + (size_t)b * N * 64;
    __shared__ unsigned short st2[64][136];
    f32x4 acc[8] = {};
    #pragma unroll
    for (int hh = 0; hh < 2; ++hh) {
        bf16x8 bfr[4][4];
        #pragma unroll
        for (int xt = 0; xt < 4; ++xt) {
            size_t xr = (size_t)(x0 + (hh * 4 + xt) * 16 + lm) * 64 + lg * 8;
            bfr[xt][0] = *(const bf16x8*)(fbb + xr);
            bfr[xt][1] = *(const bf16x8*)(fbb + xr + 32);
            bfr[xt][2] = *(const bf16x8*)(cib + xr);
            bfr[xt][3] = *(const bf16x8*)(cib + xr + 32);
        }
        #pragma unroll
        for (int xt = 0; xt < 4; ++xt)
            #pragma unroll
            for (int kt = 0; kt < 4; ++kt) {
                acc[hh * 4 + xt] = __builtin_amdgcn_mfma_f32_16x16x32_bf16(ahi[kt], bfr[xt][kt], acc[hh * 4 + xt], 0, 0, 0);
                acc[hh * 4 + xt] = __builtin_amdgcn_mfma_f32_16x16x32_bf16(alo[kt], bfr[xt][kt], acc[hh * 4 + xt], 0, 0, 0);
            }
    }
    // NO barrier: chOut != chIn (ping-pong), each wave streams straight to stores
    #pragma unroll
    for (int xt = 0; xt < 8; ++xt) {
        int xl = xt * 16 + lm;
        float v[4];
        #pragma unroll
        for (int j = 0; j < 4; ++j) {
            v[j] = acc[xt][j] + bias[j];
            if (act) v[j] = gelu_f(v[j]);
        }
        unsigned short h[4];
        #pragma unroll
        for (int j = 0; j < 4; ++j) h[j] = f2bf(v[j]);
        st2[r0 + 0][xl] = h[0];
        st2[r0 + 1][xl] = h[1];
        st2[r0 + 2][xl] = h[2];
        st2[r0 + 3][xl] = h[3];
        if (wch) {
            unsigned int* dst = (unsigned int*)(cob + (size_t)(x0 + xl) * 64 + r0);
            dst[0] = pk(h[0], h[1]);
            dst[1] = pk(h[2], h[3]);
        }
    }
    __syncthreads();  // st2 visible to moment phase (single barrier per block)
    f32x4 macc[5] = {};
    #pragma unroll
    for (int xi = 0; xi < 4; ++xi) {
        int xs = xi * 32;
        bf16x8 a = *(const bf16x8*)&st2[ro + lm][xs + lg * 8];
        #pragma unroll
        for (int ct = 0; ct < 4; ++ct)
            macc[ct] = __builtin_amdgcn_mfma_f32_16x16x32_bf16(a, wfr[xi][ct], macc[ct], 0, 0, 0);
        macc[4] = __builtin_amdgcn_mfma_f32_16x16x32_bf16(a, wfr[xi][4], macc[4], 0, 0, 0);
    }
    #pragma unroll
    for (int ct = 0; ct < 4; ++ct)
        #pragma unroll
        for (int j = 0; j < 4; ++j)
            pb[(r0 + j) * 66 + ct * 16 + lm] = f2bf(macc[ct][j]);
    if (lm == 0) {
        #pragma unroll
        for (int j = 0; j < 4; ++j) pb[(r0 + j) * 66 + 64] = f2bf(macc[4][j]);
    }
}

// ---- fused last-layer u-synthesis + fc1(gelu) + fc2 -> out ----
__global__ __launch_bounds__(256, 2) void k_synthfc(const unsigned short* __restrict__ WuBf,
                                                    const float* __restrict__ biasU,
                                                    const unsigned short* __restrict__ FTb_u,
                                                    const unsigned short* __restrict__ chIn_u,
                                                    const float* __restrict__ w1, const float* __restrict__ b1,
                                                    const float* __restrict__ w2, const float* __restrict__ b2,
                                                    float* __restrict__ out, int N) {
    int blk = blockIdx.x, b = blockIdx.y, tid = threadIdx.x;
    int lane = tid & 63, wv = tid >> 6;
    int lm = lane & 15, lg = lane >> 4;
    int ro = wv * 16;
    int r0 = ro + lg * 4;
    int x0 = blk * 128;
    int f0 = wv * 32;
    float wtmp[2][2][8];
    #pragma unroll
    for (int ft = 0; ft < 2; ++ft)
        #pragma unroll
        for (int kt = 0; kt < 2; ++kt) {
            const float* wp = w1 + (size_t)(f0 + ft * 16 + lm) * 64 + kt * 32 + lg * 8;
            *(float4*)&wtmp[ft][kt][0] = *(const float4*)wp;
            *(float4*)&wtmp[ft][kt][4] = *(const float4*)(wp + 4);
        }
    const unsigned short* Wrow = WuBf + ((size_t)b * 64 + ro + lm) * 256;
    bf16x8 ahi[4], alo[4];
    #pragma unroll
    for (int kt = 0; kt < 4; ++kt) {
        ahi[kt] = *(const bf16x8*)(Wrow + kt * 32 + lg * 8);
        alo[kt] = *(const bf16x8*)(Wrow + 128 + kt * 32 + lg * 8);
    }
    float bias[4];
    #pragma unroll
    for (int j = 0; j < 4; ++j) bias[j] = biasU[b * 64 + ro + lg * 4 + j];
    const unsigned short* fbb = FTb_u + (size_t)b * N * 64;
    const unsigned short* cib = chIn_u + (size_t)b * N * 64;
    __shared__ unsigned short st2t[128][72];
    __shared__ float red[4][8][16];
    f32x4 acc[8] = {};
    #pragma unroll
    for (int hh = 0; hh < 2; ++hh) {
        bf16x8 bfr[4][4];
        #pragma unroll
        for (int xt = 0; xt < 4; ++xt) {
            size_t xr = (size_t)(x0 + (hh * 4 + xt) * 16 + lm) * 64 + lg * 8;
            bfr[xt][0] = *(const bf16x8*)(fbb + xr);
            bfr[xt][1] = *(const bf16x8*)(fbb + xr + 32);
            bfr[xt][2] = *(const bf16x8*)(cib + xr);
            bfr[xt][3] = *(const bf16x8*)(cib + xr + 32);
        }
        #pragma unroll
        for (int xt = 0; xt < 4; ++xt)
            #pragma unroll
            for (int kt = 0; kt < 4; ++kt) {
                acc[hh * 4 + xt] = __builtin_amdgcn_mfma_f32_16x16x32_bf16(ahi[kt], bfr[xt][kt], acc[hh * 4 + xt], 0, 0, 0);
                acc[hh * 4 + xt] = __builtin_amdgcn_mfma_f32_16x16x32_bf16(alo[kt], bfr[xt][kt], acc[hh * 4 + xt], 0, 0, 0);
            }
    }
    #pragma unroll
    for (int xt = 0; xt < 8; ++xt) {
        int xl = xt * 16 + lm;
        float v0 = acc[xt][0] + bias[0];
        float v1 = acc[xt][1] + bias[1];
        float v2 = acc[xt][2] + bias[2];
        float v3 = acc[xt][3] + bias[3];
        *(unsigned int*)&st2t[xl][r0] = pk(f2bf(v0), f2bf(v1));
        *(unsigned int*)&st2t[xl][r0 + 2] = pk(f2bf(v2), f2bf(v3));
    }
    __syncthreads();
    bf16x8 whi[2][2], wlo[2][2];
    #pragma unroll
    for (int ft = 0; ft < 2; ++ft)
        #pragma unroll
        for (int kt = 0; kt < 2; ++kt)
            #pragma unroll
            for (int i = 0; i < 8; ++i) {
                unsigned short h = f2bf(wtmp[ft][kt][i]);
                whi[ft][kt][i] = (short)h;
                wlo[ft][kt][i] = (short)f2bf(wtmp[ft][kt][i] - bf2f(h));
            }
    float b1v[2][4], w2v[2][4];
    #pragma unroll
    for (int ft = 0; ft < 2; ++ft)
        #pragma unroll
        for (int j = 0; j < 4; ++j) {
            int f = f0 + ft * 16 + lg * 4 + j;
            b1v[ft][j] = b1[f];
            w2v[ft][j] = w2[f];
        }
    f32x4 facc[8][2] = {};
    #pragma unroll
    for (int xt = 0; xt < 8; ++xt) {
        int xl = xt * 16 + lm;
        bf16x8 bf0 = *(const bf16x8*)&st2t[xl][lg * 8];
        bf16x8 bf1 = *(const bf16x8*)&st2t[xl][32 + lg * 8];
        #pragma unroll
        for (int ft = 0; ft < 2; ++ft) {
            facc[xt][ft] = __builtin_amdgcn_mfma_f32_16x16x32_bf16(whi[ft][0], bf0, facc[xt][ft], 0, 0, 0);
            facc[xt][ft] = __builtin_amdgcn_mfma_f32_16x16x32_bf16(wlo[ft][0], bf0, facc[xt][ft], 0, 0, 0);
            facc[xt][ft] = __builtin_amdgcn_mfma_f32_16x16x32_bf16(whi[ft][1], bf1, facc[xt][ft], 0, 0, 0);
            facc[xt][ft] = __builtin_amdgcn_mfma_f32_16x16x32_bf16(wlo[ft][1], bf1, facc[xt][ft], 0, 0, 0);
        }
    }
    #pragma unroll
    for (int xt = 0; xt < 8; ++xt) {
        float s = 0.f;
        #pragma unroll
        for (int ft = 0; ft < 2; ++ft)
            #pragma unroll
            for (int j = 0; j < 4; ++j) {
                float v = facc[xt][ft][j] + b1v[ft][j];
                s += w2v[ft][j] * gelu_f(v);
            }
        s += __shfl_xor(s, 16, 64);
        s += __shfl_xor(s, 32, 64);
        if (lg == 0) red[wv][xt][lm] = s;
    }
    __syncthreads();
    if (tid < 128) {
        int xt = tid >> 4, lmm = tid & 15;
        float s = b2[0] + red[0][xt][lmm] + red[1][xt][lmm] + red[2][xt][lmm] + red[3][xt][lmm];
        out[(size_t)b * N + x0 + tid] = s;
    }
}

extern "C" void kernel_launch(void* const* d_in, const int* in_sizes, int n_in,
                              void* d_out, int out_size, void* d_ws, size_t ws_size,
                              hipStream_t stream) {
    const float* u_in = (const float*)d_in[0];
    const float* v_in = (const float*)d_in[1];
    const float* nodes_u = (const float*)d_in[3];
    const float* nodes_v = (const float*)d_in[4];
    const float* nwu = (const float*)d_in[5];
    const float* nwv = (const float*)d_in[6];
    const float* modes = (const float*)d_in[7];
    const float* latent = (const float*)d_in[8];
    const float* fc0uw = (const float*)d_in[9];
    const float* fc0ub = (const float*)d_in[10];
    const float* fc0vw = (const float*)d_in[11];
    const float* fc0vb = (const float*)d_in[12];
    const float* ewc = (const float*)d_in[13];
    const float* ews = (const float*)d_in[14];
    const float* ew0 = (const float*)d_in[15];
    const float* uwc = (const float*)d_in[16];
    const float* uws = (const float*)d_in[17];
    const float* uw0 = (const float*)d_in[18];
    const float* vwc = (const float*)d_in[19];
    const float* vws = (const float*)d_in[20];
    const float* vw0 = (const float*)d_in[21];
    const float* wsuw = (const float*)d_in[22];
    const float* wsub = (const float*)d_in[23];
    const float* wsvw = (const float*)d_in[24];
    const float* wsvb = (const float*)d_in[25];
    const float* fc1w = (const float*)d_in[26];
    const float* fc1b = (const float*)d_in[27];
    const float* fc2w = (const float*)d_in[28];
    const float* fc2b = (const float*)d_in[29];
    float* out = (float*)d_out;

    const int B = 4, NU = 65536, NV = 16384;
    const int CH_U = NU / 128, CH_V = NV / 128;

    unsigned short* FTb_u = (unsigned short*)d_ws;
    unsigned short* FTb_v = FTb_u + (size_t)B * NU * 64;
    unsigned short* chU0 = FTb_v + (size_t)B * NV * 64;
    unsigned short* chU1 = chU0 + (size_t)B * NU * 64;
    unsigned short* chV0 = chU1 + (size_t)B * NU * 64;
    unsigned short* chV1 = chV0 + (size_t)B * NV * 64;
    unsigned short* wbb_u = chV1 + (size_t)B * NV * 64;
    unsigned short* wbb_v = wbb_u + (size_t)B * 65 * NU;
    unsigned short* part_u = wbb_v + (size_t)B * 65 * NV;
    unsigned short* part_v = part_u + (size_t)B * CH_U * 64 * 66;
    float* momu = (float*)(part_v + (size_t)B * CH_V * 64 * 66);
    float* momv = momu + B * 64 * 66;
    unsigned short* WuBf = (unsigned short*)(momv + B * 64 * 66);
    unsigned short* WvBf = WuBf + (size_t)B * 64 * 256;
    float* biasU = (float*)(WvBf + (size_t)B * 64 * 256);
    float* biasV = biasU + B * 64;
    float* wT = biasV + B * 64;
    size_t need_T = (size_t)((char*)(wT + 6 * 393216) - (char*)d_ws);
    int use_T = (ws_size >= need_T) ? 1 : 0;

    k_prep<2><<<dim3(NU / 128, B), 256, 0, stream>>>(nodes_u, modes, latent, nwu, u_in, fc0uw, fc0ub,
                                                     FTb_u, chU0, wbb_u, part_u, NU);
    k_prep<3><<<dim3(NV / 128, B), 256, 0, stream>>>(nodes_v, modes, latent, nwv, v_in, fc0vw, fc0vb,
                                                     FTb_v, chV0, wbb_v, part_v, NV);
    if (use_T)
        k_tw<<<dim3(192, 6), 256, 0, stream>>>(ewc, ews, uwc, uws, vwc, vws, wT);

    for (int l = 0; l < 3; ++l) {
        int do_v = (l < 2) ? 1 : 0;
        k_reduce2<<<dim3(130, 2 * B), 256, 0, stream>>>(part_u, part_v, momu, momv, CH_U, CH_V, B);
        if (use_T) {
            k_buildW<<<dim3(33, B), 64, 0, stream>>>(momu, momv,
                wT + 0 * 393216 + l * 131072, wT + 1 * 393216 + l * 131072, ew0 + (size_t)l * 64 * 64,
                wT + 2 * 393216 + l * 131072, wT + 3 * 393216 + l * 131072, uw0 + (size_t)l * 64 * 64,
                wT + 4 * 393216 + l * 131072, wT + 5 * 393216 + l * 131072, vw0 + (size_t)l * 64 * 64,
                wsuw + l * 64 * 64, wsub + l * 64, wsvw + l * 64 * 64, wsvb + l * 64,
                WuBf, WvBf, biasU, biasV, do_v);
        } else {
            k_buildW_slow<<<dim3(33, B), 64, 0, stream>>>(momu, momv,
                ewc + (size_t)l * 64 * 64 * 32, ews + (size_t)l * 64 * 64 * 32, ew0 + (size_t)l * 64 * 64,
                uwc + (size_t)l * 64 * 64 * 32, uws + (size_t)l * 64 * 64 * 32, uw0 + (size_t)l * 64 * 64,
                vwc + (size_t)l * 64 * 64 * 32, vws + (size_t)l * 64 * 64 * 32, vw0 + (size_t)l * 64 * 64,
                wsuw + l * 64 * 64, wsub + l * 64, wsvw + l * 64 * 64, wsvb + l * 64,
                WuBf, WvBf, biasU, biasV, do_v);
        }
        if (l < 2) {
            int nbu = NU / 128;
            int nbx = nbu + NV / 128;
            const unsigned short* chInU = (l & 1) ? chU1 : chU0;
            unsigned short* chOutU = (l & 1) ? chU0 : chU1;
            const unsigned short* chInV = (l & 1) ? chV1 : chV0;
            unsigned short* chOutV = (l & 1) ? chV0 : chV1;
            int wch_v = (l == 0) ? 1 : 0;
            k_synth3<<<dim3(nbx, B), 256, 0, stream>>>(WuBf, WvBf, biasU, biasV,
                                                       FTb_u, FTb_v, chInU, chInV, chOutU, chOutV,
                                                       wbb_u, wbb_v, part_u, part_v,
                                                       NU, NV, nbu, 1 /*act_u*/, wch_v);
        } else {
            // l=2 reads chU0 (l0: U0->U1, l1: U1->U0)
            k_synthfc<<<dim3(NU / 128, B), 256, 0, stream>>>(WuBf, biasU, FTb_u, chU0,
                                                             fc1w, fc1b, fc2w, fc2b, out, NU);
        }
    }
}